// Round 3
// baseline (313.891 us; speedup 1.0000x reference)
//
#include <hip/hip_runtime.h>
#include <stdint.h>

#define N_NODES 207
#define N_EDGES 1722
#define N_SLOTS 288
#define L_DIM   64
#define NCSR    (2 * N_EDGES)   // 3444 CSR entries

// Round-to-nearest f32 -> bf16, returned as f32 bit pattern with low 16 zeroed
__device__ __forceinline__ unsigned int f2bf_rtn_bits_hi(float f) {
    unsigned int u = __float_as_uint(f);
    unsigned int r = u + 0x7FFFu + ((u >> 16) & 1u);
    return r & 0xFFFF0000u;
}

// ---------------------------------------------------------------------------
// K1: build CSR from the batch-invariant edge list.
//   row_start[208] ints; csr_packed[3444] uints = (edge_id<<8) | neighbor
// Self-loop edges (i==j) appear twice in node i's list -> A[i,i] += 2w (matches ref).
// ---------------------------------------------------------------------------
__global__ __launch_bounds__(256) void build_csr_kernel(
    const int* __restrict__ edge_i, const int* __restrict__ edge_j,
    int* __restrict__ row_start, unsigned int* __restrict__ csr_packed) {
    __shared__ int cnt[N_NODES];
    __shared__ int rs[N_NODES + 1];
    const int tid = threadIdx.x;

    for (int n = tid; n < N_NODES; n += 256) cnt[n] = 0;
    __syncthreads();
    for (int e = tid; e < N_EDGES; e += 256) {
        atomicAdd(&cnt[edge_i[e]], 1);
        atomicAdd(&cnt[edge_j[e]], 1);
    }
    __syncthreads();
    if (tid == 0) {
        int acc = 0;
        for (int n = 0; n < N_NODES; ++n) { rs[n] = acc; acc += cnt[n]; }
        rs[N_NODES] = acc;   // == 2*N_EDGES
    }
    __syncthreads();
    for (int n = tid; n <= N_NODES; n += 256) row_start[n] = rs[n];
    for (int n = tid; n < N_NODES; n += 256) cnt[n] = rs[n];
    __syncthreads();
    for (int e = tid; e < N_EDGES; e += 256) {
        const unsigned int i = edge_i[e], j = edge_j[e];
        const unsigned int ep = ((unsigned int)e) << 8;
        int p = atomicAdd(&cnt[i], 1);
        csr_packed[p] = ep | j;
        int q = atomicAdd(&cnt[j], 1);
        csr_packed[q] = ep | i;
    }
}

// ---------------------------------------------------------------------------
// K1b: per slot, precompute
//   coefbias[s][n] = {1 + wsl + deg, bias}             (float2)
//   eb[s][k]       = {w fp32 bits, neighbor*256 B off} (uint2)  [if eb != nullptr]
// One block per slot (288 blocks). eb removes ALL per-block slot-dependent
// packing work from K2: K2 reads it at wave-uniform addresses from read-only
// memory -> compiler emits s_load (scalar pipe, zero VALU cost).
// ---------------------------------------------------------------------------
__global__ __launch_bounds__(256) void coef_eb_kernel(
    const float* __restrict__ weight_diff, const float* __restrict__ bias_diffusion,
    const float* __restrict__ weight_self_loop,
    const int* __restrict__ row_start, const unsigned int* __restrict__ csr_packed,
    float2* __restrict__ coefbias, uint2* __restrict__ eb) {
    __shared__ float wrow[N_EDGES];
    const int s = blockIdx.x;
    for (int e = threadIdx.x; e < N_EDGES; e += 256)
        wrow[e] = weight_diff[(size_t)s * N_EDGES + e];
    __syncthreads();

    if (eb != nullptr) {
        uint2* ebs = eb + (size_t)s * NCSR;
        for (int k = threadIdx.x; k < NCSR; k += 256) {
            const unsigned int c = csr_packed[k];
            // .x = fp32 weight bits, .y = byte offset of neighbor row in fp32 LDS x
            ebs[k] = make_uint2(__float_as_uint(wrow[c >> 8]), (c & 255u) << 8);
        }
    }

    const int n = threadIdx.x;
    if (n < N_NODES) {
        float d = 0.f;
        const int e0 = row_start[n], e1 = row_start[n + 1];
        for (int k = e0; k < e1; ++k) d += wrow[csr_packed[k] >> 8];
        coefbias[s * N_NODES + n] = make_float2(
            1.f + weight_self_loop[s * N_NODES + n] + d,
            bias_diffusion[s * N_NODES + n]);
    }
}

// ---------------------------------------------------------------------------
// K2: one block (512 thr = 8 waves) per batch element.
//   out[n,l] = coef[s,n]*x[n,l] + bias[s,n] - sum_k w[k]*x[nb[k],l]
// x lives in LDS as fp32 (52,992 B -> 3 blocks/CU, 24 waves/CU).
// Per-edge lane-invariant data {w, off} streams through SGPRs via s_load
// (uniform address, read-only __restrict__ -> compiler scalarizes).
// Inner loop: v_add_u32 (addr) + ds_read_b32 + v_fmac_f32(sgpr w) = 2 VALU/edge.
// fp32 LDS gather: 64 lanes x stride-4B rows = 2 lanes/bank = conflict-free.
// ---------------------------------------------------------------------------
__global__ __launch_bounds__(512, 6) void diffusion_scalar_kernel(
    const float* __restrict__ inputs,          // (B, 2, 207, 64)
    const int*   __restrict__ ind,             // (B,)
    const int*   __restrict__ row_start,       // (208,)
    const uint2* __restrict__ eb,              // (288, 3444)
    const float2* __restrict__ coefbias,       // (288, 207)
    float* __restrict__ out) {                 // (B, 207, 64)
    __shared__ float xs[N_NODES * L_DIM];      // 52,992 B fp32

    const int b    = blockIdx.x;
    const int tid  = threadIdx.x;
    const int slot = ind[b];                   // uniform -> SGPR

    const float* xb = inputs + (size_t)b * (2 * N_NODES * L_DIM);  // channel 0

    // Stage x fp32 -> LDS, float4 global loads + float4 LDS stores (coalesced)
    const float4* xb4 = (const float4*)xb;
    float4* xs4 = (float4*)xs;
    for (int k = tid; k < (N_NODES * L_DIM) / 4; k += 512) {
        xs4[k] = xb4[k];
    }
    __syncthreads();

    const int lane  = tid & 63;
    const int lane4 = lane << 2;               // byte offset within a node row
    const int wv    = tid >> 6;                // 8 waves

    const uint2*  ebs = eb + (size_t)slot * NCSR;
    const float2* cbs = coefbias + (size_t)slot * N_NODES;
    float* ob = out + (size_t)b * (N_NODES * L_DIM);
    const char* xsb = (const char*)xs;

    for (int n = wv; n < N_NODES; n += 8) {
        const int e0 = row_start[n], e1 = row_start[n + 1];   // uniform s_load
        float s = 0.f;
        #pragma unroll 4
        for (int k = e0; k < e1; ++k) {
            const uint2 p = ebs[k];                                // s_load_dwordx2
            const float xv = *(const float*)(xsb + (p.y + lane4)); // ds_read_b32
            s = fmaf(__uint_as_float(p.x), xv, s);                 // v_fmac, w in SGPR
        }
        const float2 cb = cbs[n];                                  // uniform s_load
        const float  xg = *(const float*)(xsb + ((n << 8) + lane4));
        ob[(n << 6) + lane] = fmaf(cb.x, xg, cb.y) - s;
    }
}

// ---------------------------------------------------------------------------
// K2 (fallback, previous session's verified kernel): used only if ws is too
// small for the per-slot eb table. Identical to the 237.9 µs baseline.
// ---------------------------------------------------------------------------
__global__ __launch_bounds__(512, 8) void diffusion_gcn_fallback(
    const float* __restrict__ inputs,
    const float* __restrict__ weight_diff,
    const int*   __restrict__ ind,
    const int*   __restrict__ row_start,
    const unsigned int* __restrict__ csr_packed,
    const float2* __restrict__ coefbias,
    float* __restrict__ out) {
    __shared__ unsigned short xsh[N_NODES * L_DIM];
    __shared__ unsigned int   wnb[NCSR];
    __shared__ unsigned short rs[N_NODES + 1];

    const int b    = blockIdx.x;
    const int tid  = threadIdx.x;
    const int slot = ind[b];

    const float* xb = inputs + (size_t)b * (2 * N_NODES * L_DIM);

    const float4* xb4 = (const float4*)xb;
    for (int k = tid; k < (N_NODES * L_DIM) / 4; k += 512) {
        const float4 v = xb4[k];
        const unsigned int lo = (f2bf_rtn_bits_hi(v.x) >> 16) | f2bf_rtn_bits_hi(v.y);
        const unsigned int hi = (f2bf_rtn_bits_hi(v.z) >> 16) | f2bf_rtn_bits_hi(v.w);
        ((uint2*)xsh)[k] = make_uint2(lo, hi);
    }
    const float* wrow = weight_diff + (size_t)slot * N_EDGES;
    for (int k = tid; k < NCSR; k += 512) {
        const unsigned int c = csr_packed[k];
        wnb[k] = f2bf_rtn_bits_hi(wrow[c >> 8]) | (c & 255u);
    }
    for (int n = tid; n <= N_NODES; n += 512) rs[n] = (unsigned short)row_start[n];
    __syncthreads();

    const int lane = tid & 63;
    const int wv   = tid >> 6;
    float* ob = out + (size_t)b * (N_NODES * L_DIM);

    for (int n = wv; n < N_NODES; n += 8) {
        const int e0 = rs[n], e1 = rs[n + 1];
        float s = 0.f;
        #pragma unroll 4
        for (int k = e0; k < e1; ++k) {
            const unsigned int p = wnb[k];
            const float w  = __uint_as_float(p & 0xFFFF0000u);
            const float xv = __uint_as_float(
                (unsigned int)xsh[(p & 255u) * L_DIM + lane] << 16);
            s = fmaf(w, xv, s);
        }
        const float2 cb = coefbias[slot * N_NODES + n];
        const float  xg = xb[n * L_DIM + lane];
        ob[n * L_DIM + lane] = fmaf(cb.x, xg, cb.y) - s;
    }
}

extern "C" void kernel_launch(void* const* d_in, const int* in_sizes, int n_in,
                              void* d_out, int out_size, void* d_ws, size_t ws_size,
                              hipStream_t stream) {
    const float* inputs           = (const float*)d_in[0];
    const float* weight_diff      = (const float*)d_in[1];
    const float* bias_diffusion   = (const float*)d_in[2];
    const float* weight_self_loop = (const float*)d_in[3];
    const int*   ind              = (const int*)d_in[4];
    const int*   edge_i           = (const int*)d_in[5];
    const int*   edge_j           = (const int*)d_in[6];
    float* out = (float*)d_out;

    const int B = in_sizes[4];                 // 1024

    // ws layout (16B-aligned sections)
    char* ws = (char*)d_ws;
    int*          row_start  = (int*)ws;                              //     832 B
    unsigned int* csr_packed = (unsigned int*)(ws + 832);             //  13,776 B
    float2*       coefbias   = (float2*)(ws + 14608);                 // 476,928 B
    uint2*        eb         = (uint2*)(ws + 491536);                 // 7,934,976 B
    const size_t  WS_NEEDED  = 491536 + (size_t)N_SLOTS * NCSR * sizeof(uint2); // ~8.43 MB

    const bool use_eb = (d_ws != nullptr) && (ws_size >= WS_NEEDED);

    build_csr_kernel<<<1, 256, 0, stream>>>(edge_i, edge_j, row_start, csr_packed);
    coef_eb_kernel<<<N_SLOTS, 256, 0, stream>>>(
        weight_diff, bias_diffusion, weight_self_loop, row_start, csr_packed,
        coefbias, use_eb ? eb : nullptr);
    if (use_eb) {
        diffusion_scalar_kernel<<<B, 512, 0, stream>>>(
            inputs, ind, row_start, eb, coefbias, out);
    } else {
        diffusion_gcn_fallback<<<B, 512, 0, stream>>>(
            inputs, weight_diff, ind, row_start, csr_packed, coefbias, out);
    }
}

// Round 4
// 233.775 us; speedup vs baseline: 1.3427x; 1.3427x over previous
//
#include <hip/hip_runtime.h>
#include <stdint.h>

#define N_NODES 207
#define N_EDGES 1722
#define N_SLOTS 288
#define L_DIM   64
#define NCSR    (2 * N_EDGES)   // 3444 CSR entries

// Round-to-nearest f32 -> bf16, returned as f32 bit pattern with low 16 zeroed
__device__ __forceinline__ unsigned int f2bf_rtn_bits_hi(float f) {
    unsigned int u = __float_as_uint(f);
    unsigned int r = u + 0x7FFFu + ((u >> 16) & 1u);
    return r & 0xFFFF0000u;
}

// ---------------------------------------------------------------------------
// K1: build CSR from the batch-invariant edge list.
//   row_start[208] ints; csr_packed[3444] uints = (edge_id<<8) | neighbor
// Self-loop edges (i==j) appear twice in node i's list -> A[i,i] += 2w (matches ref).
// ---------------------------------------------------------------------------
__global__ __launch_bounds__(256) void build_csr_kernel(
    const int* __restrict__ edge_i, const int* __restrict__ edge_j,
    int* __restrict__ row_start, unsigned int* __restrict__ csr_packed) {
    __shared__ int cnt[N_NODES];
    __shared__ int rs[N_NODES + 1];
    const int tid = threadIdx.x;

    for (int n = tid; n < N_NODES; n += 256) cnt[n] = 0;
    __syncthreads();
    for (int e = tid; e < N_EDGES; e += 256) {
        atomicAdd(&cnt[edge_i[e]], 1);
        atomicAdd(&cnt[edge_j[e]], 1);
    }
    __syncthreads();
    if (tid == 0) {
        int acc = 0;
        for (int n = 0; n < N_NODES; ++n) { rs[n] = acc; acc += cnt[n]; }
        rs[N_NODES] = acc;   // == 2*N_EDGES
    }
    __syncthreads();
    for (int n = tid; n <= N_NODES; n += 256) row_start[n] = rs[n];
    for (int n = tid; n < N_NODES; n += 256) cnt[n] = rs[n];
    __syncthreads();
    for (int e = tid; e < N_EDGES; e += 256) {
        const unsigned int i = edge_i[e], j = edge_j[e];
        const unsigned int ep = ((unsigned int)e) << 8;
        int p = atomicAdd(&cnt[i], 1);
        csr_packed[p] = ep | j;
        int q = atomicAdd(&cnt[j], 1);
        csr_packed[q] = ep | i;
    }
}

// ---------------------------------------------------------------------------
// K1b: per slot, precompute
//   coefbias[s][n] = {1 + wsl + deg, bias}                      (float2)
//   eb32[s][k]     = (w bf16 in HIGH16) | (nb*128 in LOW16)     (u32)
// nb*128 = byte offset of node row in the bf16 LDS x array (<= 26,368, 15 bits;
// bits 7..14). lane*2 (bits 1..6) is disjoint -> OR == ADD in K2's addressing.
// Precomputing this table removes the per-block uncoalesced weight gather and
// the f32->bf16 pack VALU from K2 staging (K2 copies it with uint4 loads).
// ---------------------------------------------------------------------------
__global__ __launch_bounds__(256) void coef_eb_kernel(
    const float* __restrict__ weight_diff, const float* __restrict__ bias_diffusion,
    const float* __restrict__ weight_self_loop,
    const int* __restrict__ row_start, const unsigned int* __restrict__ csr_packed,
    float2* __restrict__ coefbias, unsigned int* __restrict__ eb32) {
    __shared__ float wrow[N_EDGES];
    const int s = blockIdx.x;
    for (int e = threadIdx.x; e < N_EDGES; e += 256)
        wrow[e] = weight_diff[(size_t)s * N_EDGES + e];
    __syncthreads();

    if (eb32 != nullptr) {
        unsigned int* ebs = eb32 + (size_t)s * NCSR;
        for (int k = threadIdx.x; k < NCSR; k += 256) {
            const unsigned int c = csr_packed[k];
            ebs[k] = f2bf_rtn_bits_hi(wrow[c >> 8]) | ((c & 255u) << 7);
        }
    }

    const int n = threadIdx.x;
    if (n < N_NODES) {
        float d = 0.f;
        const int e0 = row_start[n], e1 = row_start[n + 1];
        for (int k = e0; k < e1; ++k) d += wrow[csr_packed[k] >> 8];
        coefbias[s * N_NODES + n] = make_float2(
            1.f + weight_self_loop[s * N_NODES + n] + d,
            bias_diffusion[s * N_NODES + n]);
    }
}

// ---------------------------------------------------------------------------
// K2: one block (512 thr = 8 waves) per batch element.
//   out[n,l] = coef[s,n]*x[n,l] + bias[s,n] - sum_k w[k]*x[nb[k],l]
// All inner-loop data on the DS path (counted lgkmcnt waits -> pipelines;
// round-3 lesson: s_load streams force lgkmcnt(0) drains and serialize).
// Per edge: ds_read_b32 p (broadcast, merges to b64/b128 under unroll)
//           v_and (w) + v_and_or (addr) + ds_read_u16 + v_lshl + v_fmac
//           = 4 VALU + 2 LDS  (baseline was ~6 VALU + 2 LDS).
// LDS 40,688 B (same as proven baseline) -> 4 blocks/CU, 32 waves/CU.
// ---------------------------------------------------------------------------
__global__ __launch_bounds__(512, 8) void diffusion_lds_kernel(
    const float* __restrict__ inputs,          // (B, 2, 207, 64)
    const int*   __restrict__ ind,             // (B,)
    const int*   __restrict__ row_start,       // (208,)
    const unsigned int* __restrict__ eb32,     // (288, 3444) packed
    const float2* __restrict__ coefbias,       // (288, 207)
    float* __restrict__ out) {                 // (B, 207, 64)
    __shared__ unsigned short xs[N_NODES * L_DIM];   // 26,496 B (bf16)
    __shared__ unsigned int   wnb[NCSR];             // 13,776 B
    __shared__ unsigned short rs[N_NODES + 1];       //    416 B

    const int b    = blockIdx.x;
    const int tid  = threadIdx.x;
    const int slot = ind[b];                   // uniform -> SGPR

    const float* xb = inputs + (size_t)b * (2 * N_NODES * L_DIM);  // channel 0

    // Stage x (fp32 global, float4) -> bf16 LDS
    const float4* xb4 = (const float4*)xb;
    for (int k = tid; k < (N_NODES * L_DIM) / 4; k += 512) {
        const float4 v = xb4[k];
        const unsigned int lo = (f2bf_rtn_bits_hi(v.x) >> 16) | f2bf_rtn_bits_hi(v.y);
        const unsigned int hi = (f2bf_rtn_bits_hi(v.z) >> 16) | f2bf_rtn_bits_hi(v.w);
        ((uint2*)xs)[k] = make_uint2(lo, hi);
    }
    // Stage precomputed edge stream: coalesced uint4 copy (L2-resident table)
    {
        const uint4* src = (const uint4*)(eb32 + (size_t)slot * NCSR);
        uint4* dst = (uint4*)wnb;
        for (int k = tid; k < NCSR / 4; k += 512) dst[k] = src[k];
    }
    for (int n = tid; n <= N_NODES; n += 512) rs[n] = (unsigned short)row_start[n];
    __syncthreads();

    const int lane  = tid & 63;
    const unsigned int lane2 = (unsigned int)(lane << 1);  // byte off within bf16 row
    const int wv    = tid >> 6;                // 8 waves
    float* ob = out + (size_t)b * (N_NODES * L_DIM);
    const char* xsb = (const char*)xs;
    const float2* cbs = coefbias + (size_t)slot * N_NODES;

    for (int n = wv; n < N_NODES; n += 8) {
        const int e0 = rs[n], e1 = rs[n + 1];
        float s = 0.f;
        #pragma unroll 4
        for (int k = e0; k < e1; ++k) {
            const unsigned int p = wnb[k];                       // LDS broadcast
            const float w = __uint_as_float(p & 0xFFFF0000u);    // v_and (sgpr mask)
            const unsigned int off = (p & 0xFFFFu) | lane2;      // v_and_or_b32
            const unsigned int xv = *(const unsigned short*)(xsb + off);
            s = fmaf(w, __uint_as_float(xv << 16), s);           // v_lshl + v_fmac
        }
        const float2 cb = cbs[n];                                // uniform, L2-hot
        const float  xg = xb[(n << 6) + lane];                   // fp32 self term
        ob[(n << 6) + lane] = fmaf(cb.x, xg, cb.y) - s;
    }
}

// ---------------------------------------------------------------------------
// K2 (fallback, previous session's verified kernel): used only if ws is too
// small for the eb32 table. Identical to the 237.9 µs baseline.
// ---------------------------------------------------------------------------
__global__ __launch_bounds__(512, 8) void diffusion_gcn_fallback(
    const float* __restrict__ inputs,
    const float* __restrict__ weight_diff,
    const int*   __restrict__ ind,
    const int*   __restrict__ row_start,
    const unsigned int* __restrict__ csr_packed,
    const float2* __restrict__ coefbias,
    float* __restrict__ out) {
    __shared__ unsigned short xsh[N_NODES * L_DIM];
    __shared__ unsigned int   wnb[NCSR];
    __shared__ unsigned short rs[N_NODES + 1];

    const int b    = blockIdx.x;
    const int tid  = threadIdx.x;
    const int slot = ind[b];

    const float* xb = inputs + (size_t)b * (2 * N_NODES * L_DIM);

    const float4* xb4 = (const float4*)xb;
    for (int k = tid; k < (N_NODES * L_DIM) / 4; k += 512) {
        const float4 v = xb4[k];
        const unsigned int lo = (f2bf_rtn_bits_hi(v.x) >> 16) | f2bf_rtn_bits_hi(v.y);
        const unsigned int hi = (f2bf_rtn_bits_hi(v.z) >> 16) | f2bf_rtn_bits_hi(v.w);
        ((uint2*)xsh)[k] = make_uint2(lo, hi);
    }
    const float* wrow = weight_diff + (size_t)slot * N_EDGES;
    for (int k = tid; k < NCSR; k += 512) {
        const unsigned int c = csr_packed[k];
        wnb[k] = f2bf_rtn_bits_hi(wrow[c >> 8]) | (c & 255u);
    }
    for (int n = tid; n <= N_NODES; n += 512) rs[n] = (unsigned short)row_start[n];
    __syncthreads();

    const int lane = tid & 63;
    const int wv   = tid >> 6;
    float* ob = out + (size_t)b * (N_NODES * L_DIM);

    for (int n = wv; n < N_NODES; n += 8) {
        const int e0 = rs[n], e1 = rs[n + 1];
        float s = 0.f;
        #pragma unroll 4
        for (int k = e0; k < e1; ++k) {
            const unsigned int p = wnb[k];
            const float w  = __uint_as_float(p & 0xFFFF0000u);
            const float xv = __uint_as_float(
                (unsigned int)xsh[(p & 255u) * L_DIM + lane] << 16);
            s = fmaf(w, xv, s);
        }
        const float2 cb = coefbias[slot * N_NODES + n];
        const float  xg = xb[n * L_DIM + lane];
        ob[n * L_DIM + lane] = fmaf(cb.x, xg, cb.y) - s;
    }
}

extern "C" void kernel_launch(void* const* d_in, const int* in_sizes, int n_in,
                              void* d_out, int out_size, void* d_ws, size_t ws_size,
                              hipStream_t stream) {
    const float* inputs           = (const float*)d_in[0];
    const float* weight_diff      = (const float*)d_in[1];
    const float* bias_diffusion   = (const float*)d_in[2];
    const float* weight_self_loop = (const float*)d_in[3];
    const int*   ind              = (const int*)d_in[4];
    const int*   edge_i           = (const int*)d_in[5];
    const int*   edge_j           = (const int*)d_in[6];
    float* out = (float*)d_out;

    const int B = in_sizes[4];                 // 1024

    // ws layout (16B-aligned sections)
    char* ws = (char*)d_ws;
    int*          row_start  = (int*)ws;                              //     832 B
    unsigned int* csr_packed = (unsigned int*)(ws + 832);             //  13,776 B
    float2*       coefbias   = (float2*)(ws + 14608);                 // 476,928 B
    unsigned int* eb32       = (unsigned int*)(ws + 491536);          // 3,967,488 B
    const size_t  WS_NEEDED  = 491536 + (size_t)N_SLOTS * NCSR * sizeof(unsigned int);

    const bool use_eb = (d_ws != nullptr) && (ws_size >= WS_NEEDED);

    build_csr_kernel<<<1, 256, 0, stream>>>(edge_i, edge_j, row_start, csr_packed);
    coef_eb_kernel<<<N_SLOTS, 256, 0, stream>>>(
        weight_diff, bias_diffusion, weight_self_loop, row_start, csr_packed,
        coefbias, use_eb ? eb32 : nullptr);
    if (use_eb) {
        diffusion_lds_kernel<<<B, 512, 0, stream>>>(
            inputs, ind, row_start, eb32, coefbias, out);
    } else {
        diffusion_gcn_fallback<<<B, 512, 0, stream>>>(
            inputs, weight_diff, ind, row_start, csr_packed, coefbias, out);
    }
}